// Round 1
// baseline (533.946 us; speedup 1.0000x reference)
//
#include <hip/hip_runtime.h>
#include <cstdint>
#include <cstddef>

#define T_TOK 4096
#define DM 1024
#define HS 4096
#define NE 8
#define MAXROWS 9216   // 8192 pairs + 8*128 padding worst case
#define MAXTILES 72    // MAXROWS/128

typedef __attribute__((ext_vector_type(8))) short short8;
typedef __attribute__((ext_vector_type(4))) float floatx4;

__device__ __forceinline__ unsigned short f2bf(float f) {
  union { float f; unsigned u; } v; v.f = f;
  unsigned r = (v.u + 0x7fffu + ((v.u >> 16) & 1u)) >> 16;
  return (unsigned short)r;
}

__device__ __forceinline__ void gload_lds16(const void* g, void* l) {
  __builtin_amdgcn_global_load_lds((const __attribute__((address_space(1))) void*)g,
                                   (__attribute__((address_space(3))) void*)l, 16, 0, 0);
}

// ---------------- small kernels ----------------

__global__ void k_init(int* counts, int* cursor, unsigned* list) {
  int i = blockIdx.x * 256 + threadIdx.x;
  if (i < NE) { counts[i] = 0; cursor[i] = 0; }
  if (i < MAXROWS) list[i] = 0xFFFFFFFFu;
}

__global__ void k_route(const float* __restrict__ x, const float* __restrict__ rw,
                        const float* __restrict__ rb, const float* __restrict__ lw,
                        const float* __restrict__ lb, int* __restrict__ top_i,
                        float* __restrict__ top_p, int* __restrict__ counts) {
  int t = blockIdx.x * 4 + (threadIdx.x >> 6);
  int lane = threadIdx.x & 63;
  const float4* xt = (const float4*)(x + (size_t)t * DM);
  float4 xv[4];
#pragma unroll
  for (int j = 0; j < 4; j++) xv[j] = xt[lane * 4 + j];
  float dots[12];
#pragma unroll
  for (int r = 0; r < 12; r++) {
    const float4* wr = (const float4*)(r < 4 ? lw + r * DM : rw + (r - 4) * DM);
    float s = 0.f;
#pragma unroll
    for (int j = 0; j < 4; j++) {
      float4 w = wr[lane * 4 + j];
      s += xv[j].x * w.x + xv[j].y * w.y + xv[j].z * w.z + xv[j].w * w.w;
    }
#pragma unroll
    for (int o = 32; o > 0; o >>= 1) s += __shfl_xor(s, o, 64);
    dots[r] = s;
  }
  if (lane == 0) {
    float lp[4]; float m = -1e30f;
#pragma unroll
    for (int i = 0; i < 4; i++) { lp[i] = dots[i] + lb[i]; m = fmaxf(m, lp[i]); }
    float sum = 0.f;
#pragma unroll
    for (int i = 0; i < 4; i++) { lp[i] = expf(lp[i] - m); sum += lp[i]; }
#pragma unroll
    for (int i = 0; i < 4; i++) lp[i] /= sum;
    float ew[4];
    ew[0] = lp[0] + lp[1]; ew[1] = lp[1] + lp[2]; ew[2] = lp[2] + lp[3]; ew[3] = lp[3];
    float r8[8];
#pragma unroll
    for (int e = 0; e < 8; e++) r8[e] = dots[4 + e] + rb[e] + 0.1f * ew[e & 3];
    int e0 = 0;
#pragma unroll
    for (int e = 1; e < 8; e++) if (r8[e] > r8[e0]) e0 = e;
    int e1 = (e0 == 0) ? 1 : 0;
#pragma unroll
    for (int e = 0; e < 8; e++) if (e != e0 && r8[e] > r8[e1]) e1 = e;
    float tt = expf(r8[e1] - r8[e0]);
    float w0 = 1.f / (1.f + tt);
    float w1 = tt / (1.f + tt);
    top_i[t * 2] = e0; top_i[t * 2 + 1] = e1;
    top_p[t * 2] = w0; top_p[t * 2 + 1] = w1;
    atomicAdd(&counts[e0], 1); atomicAdd(&counts[e1], 1);
  }
}

__global__ void k_offsets(const int* counts, int* off) {
  if (threadIdx.x == 0) {
    int acc = 0;
    for (int e = 0; e < NE; e++) {
      off[e] = acc;
      int p = ((counts[e] + 127) >> 7) << 7;
      acc += p;
    }
    off[NE] = acc;
  }
}

__global__ void k_scatter(const int* __restrict__ top_i, const int* __restrict__ off,
                          int* cursor, unsigned* __restrict__ list) {
  int t = blockIdx.x * 256 + threadIdx.x;
  if (t >= T_TOK) return;
#pragma unroll
  for (int k = 0; k < 2; k++) {
    int e = top_i[t * 2 + k];
    int pos = atomicAdd(&cursor[e], 1);
    list[off[e] + pos] = (unsigned)(t * 2 + k);
  }
}

__global__ void k_cvt_x(const float* __restrict__ x, unsigned short* __restrict__ xb) {
  int i = blockIdx.x * 256 + threadIdx.x;  // 4 elems per thread
  float4 v = ((const float4*)x)[i];
  union { unsigned short us[4]; uint2 u2; } o;
  o.us[0] = f2bf(v.x); o.us[1] = f2bf(v.y); o.us[2] = f2bf(v.z); o.us[3] = f2bf(v.w);
  ((uint2*)xb)[i] = o.u2;
}

// transpose+convert: src f32 [e][K][N] -> dst bf16 [e][N][K]
__global__ void k_transpose_bf16(const float* __restrict__ src, unsigned short* __restrict__ dst,
                                 int K, int N) {
  __shared__ float tile[64][65];
  const float* s = src + (size_t)blockIdx.z * K * N;
  unsigned short* d = dst + (size_t)blockIdx.z * K * N;
  int n0 = blockIdx.x * 64, k0 = blockIdx.y * 64;
  int r = threadIdx.x >> 6, c = threadIdx.x & 63;
#pragma unroll
  for (int j = 0; j < 16; j++) tile[r + j * 4][c] = s[(size_t)(k0 + r + j * 4) * N + n0 + c];
  __syncthreads();
#pragma unroll
  for (int j = 0; j < 16; j++) d[(size_t)(n0 + r + j * 4) * K + k0 + c] = f2bf(tile[c][r + j * 4]);
}

__global__ void k_init_out(const int* __restrict__ top_i, const float* __restrict__ top_p,
                           const float* __restrict__ b2, float* __restrict__ out) {
  int i = blockIdx.x * 256 + threadIdx.x;
  int t = i >> 10, d = i & 1023;
  int e0 = top_i[t * 2], e1 = top_i[t * 2 + 1];
  out[i] = top_p[t * 2] * b2[e0 * DM + d] + top_p[t * 2 + 1] * b2[e1 * DM + d];
}

// ---------------- grouped GEMM ----------------
// MODE 0: h = gelu(xg @ w1t^T + b1)  (A gathered via list)   C bf16 -> Hout
// MODE 1: out += p * (h @ w2t^T)     (A linear rows)         atomicAdd f32
template <int MODE>
__global__ __launch_bounds__(256, 2) void k_gemm(
    const unsigned short* __restrict__ Abase,
    const unsigned short* __restrict__ Wt,   // [E][N][K] bf16
    const int* __restrict__ off, const unsigned* __restrict__ list,
    const float* __restrict__ b1, const float* __restrict__ top_p,
    unsigned short* __restrict__ Hout, float* __restrict__ out,
    int K, int N) {
  int r0 = blockIdx.x * 128;
  int total = off[NE];
  if (r0 >= total) return;
  int e = 0;
  while (r0 >= off[e + 1]) ++e;
  int n0 = blockIdx.y * 128;

  __shared__ __align__(16) unsigned short lA[128 * 32];
  __shared__ __align__(16) unsigned short lB[128 * 32];
  __shared__ float sP[128];
  __shared__ int sTok[128];

  int tid = threadIdx.x;
  int srow = tid >> 2;         // 0..63
  int koff = (tid & 3) * 8;    // bf16 elements

  const unsigned short* srcA[2];
#pragma unroll
  for (int c = 0; c < 2; c++) {
    int row = c * 64 + srow;
    size_t arow;
    if (MODE == 0) {
      unsigned pair = list[r0 + row];
      arow = (pair == 0xFFFFFFFFu) ? 0 : (size_t)(pair >> 1);
    } else {
      arow = (size_t)(r0 + row);
    }
    srcA[c] = Abase + arow * K + koff;
  }
  const unsigned short* srcB[2];
#pragma unroll
  for (int c = 0; c < 2; c++)
    srcB[c] = Wt + ((size_t)e * N + n0 + c * 64 + srow) * K + koff;

  if (MODE == 1 && tid < 128) {
    unsigned pair = list[r0 + tid];
    if (pair == 0xFFFFFFFFu) { sTok[tid] = -1; sP[tid] = 0.f; }
    else { sTok[tid] = (int)(pair >> 1); sP[tid] = top_p[pair]; }
  }

  floatx4 acc[4][4] = {};
  int lane = tid & 63;
  int w = tid >> 6;
  int wm = w >> 1, wn = w & 1;
  int lr = lane & 15, kq = lane >> 4;
  const short8* pA = (const short8*)lA;
  const short8* pB = (const short8*)lB;

  for (int k0 = 0; k0 < K; k0 += 32) {
    __syncthreads();
#pragma unroll
    for (int c = 0; c < 2; c++) {
      gload_lds16(srcA[c] + k0, &lA[(c * 64 + srow) * 32 + koff]);
      gload_lds16(srcB[c] + k0, &lB[(c * 64 + srow) * 32 + koff]);
    }
    __syncthreads();
    short8 a[4], b[4];
#pragma unroll
    for (int i = 0; i < 4; i++) a[i] = pA[((wm * 64 + i * 16 + lr) * 32 + kq * 8) >> 3];
#pragma unroll
    for (int j = 0; j < 4; j++) b[j] = pB[((wn * 64 + j * 16 + lr) * 32 + kq * 8) >> 3];
#pragma unroll
    for (int i = 0; i < 4; i++)
#pragma unroll
      for (int j = 0; j < 4; j++)
        acc[i][j] = __builtin_amdgcn_mfma_f32_16x16x32_bf16(a[i], b[j], acc[i][j], 0, 0, 0);
  }

  int rbase = wm * 64 + kq * 4;
  int cbase = wn * 64 + lr;
  if (MODE == 0) {
#pragma unroll
    for (int i = 0; i < 4; i++)
#pragma unroll
      for (int j = 0; j < 4; j++)
#pragma unroll
        for (int g = 0; g < 4; g++) {
          int row = rbase + i * 16 + g;
          int col = cbase + j * 16;
          float v = acc[i][j][g] + b1[e * HS + n0 + col];
          v = 0.5f * v * (1.f + erff(v * 0.70710678118f));
          Hout[(size_t)(r0 + row) * (size_t)N + n0 + col] = f2bf(v);
        }
  } else {
#pragma unroll
    for (int i = 0; i < 4; i++)
#pragma unroll
      for (int j = 0; j < 4; j++)
#pragma unroll
        for (int g = 0; g < 4; g++) {
          int row = rbase + i * 16 + g;
          int col = cbase + j * 16;
          int tok = sTok[row];
          if (tok >= 0)
            atomicAdd(&out[(size_t)tok * DM + n0 + col], sP[row] * acc[i][j][g]);
        }
  }
}

// ---------------- launch ----------------

extern "C" void kernel_launch(void* const* d_in, const int* in_sizes, int n_in,
                              void* d_out, int out_size, void* d_ws, size_t ws_size,
                              hipStream_t stream) {
  const float* x  = (const float*)d_in[0];
  const float* rw = (const float*)d_in[1];
  const float* rb = (const float*)d_in[2];
  const float* lw = (const float*)d_in[3];
  const float* lb = (const float*)d_in[4];
  const float* w1 = (const float*)d_in[5];
  const float* b1 = (const float*)d_in[6];
  const float* w2 = (const float*)d_in[7];
  const float* b2 = (const float*)d_in[8];
  float* out = (float*)d_out;
  char* ws = (char*)d_ws;

  int* counts = (int*)ws;
  int* cursor = (int*)(ws + 32);
  int* off    = (int*)(ws + 64);
  int* top_i  = (int*)(ws + 128);
  float* top_p = (float*)(ws + 128 + 32768);
  unsigned* list = (unsigned*)(ws + 65792);
  unsigned short* xb = (unsigned short*)(ws + 102912);
  unsigned short* wt = (unsigned short*)(ws + 102912 + 8388608);            // 64 MB shared w1t/w2t
  unsigned short* h  = (unsigned short*)(ws + 102912 + 8388608 + 67108864); // 72 MB

  k_init<<<dim3((MAXROWS + 255) / 256), dim3(256), 0, stream>>>(counts, cursor, list);
  k_route<<<dim3(T_TOK / 4), dim3(256), 0, stream>>>(x, rw, rb, lw, lb, top_i, top_p, counts);
  k_offsets<<<dim3(1), dim3(64), 0, stream>>>(counts, off);
  k_scatter<<<dim3(T_TOK / 256), dim3(256), 0, stream>>>(top_i, off, cursor, list);
  k_cvt_x<<<dim3(T_TOK * DM / 4 / 256), dim3(256), 0, stream>>>(x, xb);
  k_transpose_bf16<<<dim3(HS / 64, DM / 64, NE), dim3(256), 0, stream>>>(w1, wt, DM, HS);
  k_gemm<0><<<dim3(MAXTILES, HS / 128), dim3(256), 0, stream>>>(
      xb, wt, off, list, b1, top_p, h, nullptr, DM, HS);
  k_transpose_bf16<<<dim3(DM / 64, HS / 64, NE), dim3(256), 0, stream>>>(w2, wt, HS, DM);
  k_init_out<<<dim3(T_TOK * DM / 256), dim3(256), 0, stream>>>(top_i, top_p, b2, out);
  k_gemm<1><<<dim3(MAXTILES, DM / 128), dim3(256), 0, stream>>>(
      h, wt, off, list, nullptr, top_p, nullptr, out, HS, DM);
}

// Round 2
// 515.381 us; speedup vs baseline: 1.0360x; 1.0360x over previous
//
#include <hip/hip_runtime.h>
#include <cstdint>
#include <cstddef>

#define T_TOK 4096
#define DM 1024
#define HS 4096
#define NE 8
#define MAXROWS 9216   // 8192 pairs + 8*128 padding worst case
#define MAXTILES 72    // MAXROWS/128

typedef __attribute__((ext_vector_type(8))) short short8;
typedef __attribute__((ext_vector_type(4))) float floatx4;

__device__ __forceinline__ unsigned short f2bf(float f) {
  union { float f; unsigned u; } v; v.f = f;
  unsigned r = (v.u + 0x7fffu + ((v.u >> 16) & 1u)) >> 16;
  return (unsigned short)r;
}

__device__ __forceinline__ void gload_lds16(const void* g, void* l) {
  __builtin_amdgcn_global_load_lds((const __attribute__((address_space(1))) void*)g,
                                   (__attribute__((address_space(3))) void*)l, 16, 0, 0);
}

// ---------------- small kernels ----------------

__global__ void k_init(int* counts, int* cursor, unsigned* list) {
  int i = blockIdx.x * 256 + threadIdx.x;
  if (i < NE) { counts[i] = 0; cursor[i] = 0; }
  if (i < MAXROWS) list[i] = 0xFFFFFFFFu;
}

__global__ void k_route(const float* __restrict__ x, const float* __restrict__ rw,
                        const float* __restrict__ rb, const float* __restrict__ lw,
                        const float* __restrict__ lb, int* __restrict__ top_i,
                        float* __restrict__ top_p, int* __restrict__ counts) {
  int t = blockIdx.x * 4 + (threadIdx.x >> 6);
  int lane = threadIdx.x & 63;
  const float4* xt = (const float4*)(x + (size_t)t * DM);
  float4 xv[4];
#pragma unroll
  for (int j = 0; j < 4; j++) xv[j] = xt[lane * 4 + j];
  float dots[12];
#pragma unroll
  for (int r = 0; r < 12; r++) {
    const float4* wr = (const float4*)(r < 4 ? lw + r * DM : rw + (r - 4) * DM);
    float s = 0.f;
#pragma unroll
    for (int j = 0; j < 4; j++) {
      float4 w = wr[lane * 4 + j];
      s += xv[j].x * w.x + xv[j].y * w.y + xv[j].z * w.z + xv[j].w * w.w;
    }
#pragma unroll
    for (int o = 32; o > 0; o >>= 1) s += __shfl_xor(s, o, 64);
    dots[r] = s;
  }
  if (lane == 0) {
    float lp[4]; float m = -1e30f;
#pragma unroll
    for (int i = 0; i < 4; i++) { lp[i] = dots[i] + lb[i]; m = fmaxf(m, lp[i]); }
    float sum = 0.f;
#pragma unroll
    for (int i = 0; i < 4; i++) { lp[i] = expf(lp[i] - m); sum += lp[i]; }
#pragma unroll
    for (int i = 0; i < 4; i++) lp[i] /= sum;
    float ew[4];
    ew[0] = lp[0] + lp[1]; ew[1] = lp[1] + lp[2]; ew[2] = lp[2] + lp[3]; ew[3] = lp[3];
    float r8[8];
#pragma unroll
    for (int e = 0; e < 8; e++) r8[e] = dots[4 + e] + rb[e] + 0.1f * ew[e & 3];
    int e0 = 0;
#pragma unroll
    for (int e = 1; e < 8; e++) if (r8[e] > r8[e0]) e0 = e;
    int e1 = (e0 == 0) ? 1 : 0;
#pragma unroll
    for (int e = 0; e < 8; e++) if (e != e0 && r8[e] > r8[e1]) e1 = e;
    float tt = expf(r8[e1] - r8[e0]);
    float w0 = 1.f / (1.f + tt);
    float w1 = tt / (1.f + tt);
    top_i[t * 2] = e0; top_i[t * 2 + 1] = e1;
    top_p[t * 2] = w0; top_p[t * 2 + 1] = w1;
    atomicAdd(&counts[e0], 1); atomicAdd(&counts[e1], 1);
  }
}

__global__ void k_offsets(const int* counts, int* off) {
  if (threadIdx.x == 0) {
    int acc = 0;
    for (int e = 0; e < NE; e++) {
      off[e] = acc;
      int p = ((counts[e] + 127) >> 7) << 7;
      acc += p;
    }
    off[NE] = acc;
  }
}

__global__ void k_scatter(const int* __restrict__ top_i, const int* __restrict__ off,
                          int* cursor, unsigned* __restrict__ list) {
  int t = blockIdx.x * 256 + threadIdx.x;
  if (t >= T_TOK) return;
#pragma unroll
  for (int k = 0; k < 2; k++) {
    int e = top_i[t * 2 + k];
    int pos = atomicAdd(&cursor[e], 1);
    list[off[e] + pos] = (unsigned)(t * 2 + k);
  }
}

__global__ void k_cvt_x(const float* __restrict__ x, unsigned short* __restrict__ xb) {
  int i = blockIdx.x * 256 + threadIdx.x;  // 4 elems per thread
  float4 v = ((const float4*)x)[i];
  union { unsigned short us[4]; uint2 u2; } o;
  o.us[0] = f2bf(v.x); o.us[1] = f2bf(v.y); o.us[2] = f2bf(v.z); o.us[3] = f2bf(v.w);
  ((uint2*)xb)[i] = o.u2;
}

// transpose+convert: src f32 [e][K][N] -> dst bf16 [e][N][K]
// vectorized: float4 reads, uint2 (4xbf16) writes, pad-65 LDS (2-way max)
__global__ void k_transpose_bf16(const float* __restrict__ src, unsigned short* __restrict__ dst,
                                 int K, int N) {
  __shared__ float tile[64][65];
  const float* s = src + (size_t)blockIdx.z * K * N;
  unsigned short* d = dst + (size_t)blockIdx.z * K * N;
  int n0 = blockIdx.x * 64, k0 = blockIdx.y * 64;
  int tr = threadIdx.x >> 4;          // 0..15
  int tc = (threadIdx.x & 15) * 4;    // 0,4,...,60
#pragma unroll
  for (int j = 0; j < 4; j++) {
    int row = tr + j * 16;
    float4 v = *(const float4*)&s[(size_t)(k0 + row) * N + n0 + tc];
    tile[row][tc + 0] = v.x; tile[row][tc + 1] = v.y;
    tile[row][tc + 2] = v.z; tile[row][tc + 3] = v.w;
  }
  __syncthreads();
#pragma unroll
  for (int j = 0; j < 4; j++) {
    int n = tr + j * 16;
    union { unsigned short us[4]; uint2 u2; } o;
#pragma unroll
    for (int i = 0; i < 4; i++) o.us[i] = f2bf(tile[tc + i][n]);
    *(uint2*)&d[(size_t)(n0 + n) * K + k0 + tc] = o.u2;
  }
}

__global__ void k_init_out(const int* __restrict__ top_i, const float* __restrict__ top_p,
                           const float* __restrict__ b2, float* __restrict__ out) {
  int i = blockIdx.x * 256 + threadIdx.x;
  int t = i >> 10, d = i & 1023;
  int e0 = top_i[t * 2], e1 = top_i[t * 2 + 1];
  out[i] = top_p[t * 2] * b2[e0 * DM + d] + top_p[t * 2 + 1] * b2[e1 * DM + d];
}

// ---------------- grouped GEMM ----------------
// 128x128 tile, BK=32, double-buffered LDS, 2-phase prefetch, chunk-XOR swizzle.
// MODE 0: h = gelu(xg @ w1t^T + b1)  (A gathered via list)   C bf16 -> Hout
// MODE 1: out += p * (h @ w2t^T)     (A linear rows)         atomicAdd f32
template <int MODE>
__global__ __launch_bounds__(256, 4) void k_gemm(
    const unsigned short* __restrict__ Abase,
    const unsigned short* __restrict__ Wt,   // [E][N][K] bf16
    const int* __restrict__ off, const unsigned* __restrict__ list,
    const float* __restrict__ b1, const float* __restrict__ top_p,
    unsigned short* __restrict__ Hout, float* __restrict__ out,
    int K, int N) {
  // XCD-aware chunked swizzle on flat block id (nwg % 8 == 0 for both grids)
  int nx = gridDim.x;                                 // n-tiles
  int flat = blockIdx.y * nx + blockIdx.x;
  int cpx = (nx * gridDim.y) >> 3;
  int swz = (flat & 7) * cpx + (flat >> 3);
  int n0 = (swz % nx) * 128;
  int r0 = (swz / nx) * 128;

  int total = off[NE];
  if (r0 >= total) return;
  int e = 0;
  while (r0 >= off[e + 1]) ++e;

  __shared__ __align__(16) unsigned short lA[2][128 * 32];
  __shared__ __align__(16) unsigned short lB[2][128 * 32];
  __shared__ float sP[128];
  __shared__ int sTok[128];

  int tid = threadIdx.x;
  int srow = tid >> 2;                 // 0..63 (LDS row within 64-row half)
  // rule-21 swizzle: LDS dest stays linear (chunk = tid&3); the global SOURCE
  // fetches chunk (tid&3) ^ key(row); reads undo it with the same key.
  int key_s = (srow >> 1) & 3;
  int koff_src = (((tid & 3) ^ key_s) * 8);   // bf16 elements within 32-wide K row
  int kdst = (tid & 3) * 8;

  const unsigned short* srcA[2];
#pragma unroll
  for (int c = 0; c < 2; c++) {
    int row = c * 64 + srow;
    size_t arow;
    if (MODE == 0) {
      unsigned pair = list[r0 + row];
      arow = (pair == 0xFFFFFFFFu) ? 0 : (size_t)(pair >> 1);
    } else {
      arow = (size_t)(r0 + row);
    }
    srcA[c] = Abase + arow * K + koff_src;
  }
  const unsigned short* srcB[2];
#pragma unroll
  for (int c = 0; c < 2; c++)
    srcB[c] = Wt + ((size_t)e * N + n0 + c * 64 + srow) * K + koff_src;

  if (MODE == 1 && tid < 128) {
    unsigned pair = list[r0 + tid];
    if (pair == 0xFFFFFFFFu) { sTok[tid] = -1; sP[tid] = 0.f; }
    else { sTok[tid] = (int)(pair >> 1); sP[tid] = top_p[pair]; }
  }

  floatx4 acc[4][4] = {};
  int lane = tid & 63;
  int w = tid >> 6;
  int wm = w >> 1, wn = w & 1;
  int lr = lane & 15, kq = lane >> 4;
  int kx = kq ^ ((lr >> 1) & 3);       // swizzled 16B-chunk slot for reads

#define STAGE(BUF, KK)                                                        \
  do {                                                                        \
    _Pragma("unroll")                                                         \
    for (int c = 0; c < 2; c++) {                                             \
      gload_lds16(srcA[c] + (KK), &lA[BUF][(c * 64 + srow) * 32 + kdst]);     \
      gload_lds16(srcB[c] + (KK), &lB[BUF][(c * 64 + srow) * 32 + kdst]);     \
    }                                                                         \
  } while (0)

  // prologue
  STAGE(0, 0);
  __syncthreads();   // vmcnt(0)+lgkmcnt(0)+barrier

  int cur = 0;
  for (int k0 = 0; k0 < K; k0 += 32) {
    if (k0 + 32 < K) STAGE(cur ^ 1, k0 + 32);  // prefetch next tile (in flight during MFMA)
    const short8* pA = (const short8*)lA[cur];
    const short8* pB = (const short8*)lB[cur];
    short8 a[4], b[4];
#pragma unroll
    for (int i = 0; i < 4; i++) a[i] = pA[(wm * 64 + i * 16 + lr) * 4 + kx];
#pragma unroll
    for (int j = 0; j < 4; j++) b[j] = pB[(wn * 64 + j * 16 + lr) * 4 + kx];
#pragma unroll
    for (int i = 0; i < 4; i++)
#pragma unroll
      for (int j = 0; j < 4; j++)
        acc[i][j] = __builtin_amdgcn_mfma_f32_16x16x32_bf16(a[i], b[j], acc[i][j], 0, 0, 0);
    __syncthreads();   // single barrier per K-step; drains prefetch vmcnt
    cur ^= 1;
  }
#undef STAGE

  int rbase = wm * 64 + kq * 4;
  int cbase = wn * 64 + lr;
  if (MODE == 0) {
#pragma unroll
    for (int i = 0; i < 4; i++)
#pragma unroll
      for (int j = 0; j < 4; j++)
#pragma unroll
        for (int g = 0; g < 4; g++) {
          int row = rbase + i * 16 + g;
          int col = cbase + j * 16;
          float v = acc[i][j][g] + b1[e * HS + n0 + col];
          v = 0.5f * v * (1.f + erff(v * 0.70710678118f));
          Hout[(size_t)(r0 + row) * (size_t)N + n0 + col] = f2bf(v);
        }
  } else {
#pragma unroll
    for (int i = 0; i < 4; i++)
#pragma unroll
      for (int j = 0; j < 4; j++)
#pragma unroll
        for (int g = 0; g < 4; g++) {
          int row = rbase + i * 16 + g;
          int col = cbase + j * 16;
          int tok = sTok[row];
          if (tok >= 0)
            atomicAdd(&out[(size_t)tok * DM + n0 + col], sP[row] * acc[i][j][g]);
        }
  }
}

// ---------------- launch ----------------

extern "C" void kernel_launch(void* const* d_in, const int* in_sizes, int n_in,
                              void* d_out, int out_size, void* d_ws, size_t ws_size,
                              hipStream_t stream) {
  const float* x  = (const float*)d_in[0];
  const float* rw = (const float*)d_in[1];
  const float* rb = (const float*)d_in[2];
  const float* lw = (const float*)d_in[3];
  const float* lb = (const float*)d_in[4];
  const float* w1 = (const float*)d_in[5];
  const float* b1 = (const float*)d_in[6];
  const float* w2 = (const float*)d_in[7];
  const float* b2 = (const float*)d_in[8];
  float* out = (float*)d_out;
  char* ws = (char*)d_ws;

  int* counts = (int*)ws;
  int* cursor = (int*)(ws + 32);
  int* off    = (int*)(ws + 64);
  int* top_i  = (int*)(ws + 128);
  float* top_p = (float*)(ws + 128 + 32768);
  unsigned* list = (unsigned*)(ws + 65792);
  unsigned short* xb = (unsigned short*)(ws + 102912);
  unsigned short* wt = (unsigned short*)(ws + 102912 + 8388608);            // 64 MB shared w1t/w2t
  unsigned short* h  = (unsigned short*)(ws + 102912 + 8388608 + 67108864); // 72 MB

  k_init<<<dim3((MAXROWS + 255) / 256), dim3(256), 0, stream>>>(counts, cursor, list);
  k_route<<<dim3(T_TOK / 4), dim3(256), 0, stream>>>(x, rw, rb, lw, lb, top_i, top_p, counts);
  k_offsets<<<dim3(1), dim3(64), 0, stream>>>(counts, off);
  k_scatter<<<dim3(T_TOK / 256), dim3(256), 0, stream>>>(top_i, off, cursor, list);
  k_cvt_x<<<dim3(T_TOK * DM / 4 / 256), dim3(256), 0, stream>>>(x, xb);
  k_transpose_bf16<<<dim3(HS / 64, DM / 64, NE), dim3(256), 0, stream>>>(w1, wt, DM, HS);
  k_gemm<0><<<dim3(HS / 128, MAXTILES), dim3(256), 0, stream>>>(
      xb, wt, off, list, b1, top_p, h, nullptr, DM, HS);
  k_transpose_bf16<<<dim3(DM / 64, HS / 64, NE), dim3(256), 0, stream>>>(w2, wt, HS, DM);
  k_init_out<<<dim3(T_TOK * DM / 256), dim3(256), 0, stream>>>(top_i, top_p, b2, out);
  k_gemm<1><<<dim3(DM / 128, MAXTILES), dim3(256), 0, stream>>>(
      h, wt, off, list, nullptr, top_p, nullptr, out, HS, DM);
}